// Round 1
// baseline (728.660 us; speedup 1.0000x reference)
//
#include <hip/hip_runtime.h>

// Subtraction op (SAN): x (16,64,56,56) f32 -> out (16,64,49,3136) f32
// out[n][c][k][h*56+w] = x[n][c][h][w] - (inb ? x[n][c][h+di][w+dj] : 0)
// di = k/7 - 3, dj = k%7 - 3.
//
// Write-BW bound: 629 MB out vs 12.8 MB in. Each (n,c) plane is 12.5 KB ->
// L1-resident, so neighbor reads are ~free. Block = one (n,c,k) plane,
// contiguous float4 stores.

#define NC   1024   // 16*64
#define KK   49
#define HW   56
#define LL   3136   // 56*56
#define L4   784    // LL/4

__global__ __launch_bounds__(256) void sub_kernel(const float* __restrict__ x,
                                                  float* __restrict__ out) {
    const int b  = blockIdx.x;          // [0, NC*KK)
    const int k  = b % KK;
    const int nc = b / KK;
    const int di = (k / 7) - 3;
    const int dj = (k % 7) - 3;

    const float* __restrict__ xp = x + (size_t)nc * LL;
    float4* __restrict__ op = (float4*)out + (size_t)b * L4;

    for (int t = threadIdx.x; t < L4; t += 256) {
        const int h  = t / 14;          // 14 float4 per row of 56
        const int w0 = (t - h * 14) * 4;

        const int  hs    = h + di;
        const bool rowOK = (unsigned)hs < HW;
        const int  hc    = rowOK ? hs : 0;          // clamped, always in-bounds
        const float* __restrict__ srow = xp + hc * HW;

        const float4 c4 = *(const float4*)(xp + h * HW + w0);
        const float cc[4] = {c4.x, c4.y, c4.z, c4.w};

        float r[4];
        #pragma unroll
        for (int e = 0; e < 4; ++e) {
            const int  ws   = w0 + e + dj;
            const bool colOK = (unsigned)ws < HW;
            const int  wc   = colOK ? ws : 0;       // clamped address
            const float s   = srow[wc];             // always in-bounds load
            r[e] = cc[e] - ((rowOK && colOK) ? s : 0.0f);
        }
        op[t] = make_float4(r[0], r[1], r[2], r[3]);
    }
}

extern "C" void kernel_launch(void* const* d_in, const int* in_sizes, int n_in,
                              void* d_out, int out_size, void* d_ws, size_t ws_size,
                              hipStream_t stream) {
    const float* x = (const float*)d_in[0];
    float* out = (float*)d_out;
    sub_kernel<<<dim3(NC * KK), dim3(256), 0, stream>>>(x, out);
}